// Round 2
// baseline (14030.289 us; speedup 1.0000x reference)
//
#include <hip/hip_runtime.h>
#include <hip/hip_bf16.h>
#include <cstddef>

#define B_ 128
#define T_ 512
#define I_ 64
#define H_ 512

typedef __attribute__((ext_vector_type(8))) short short8v;
typedef __attribute__((ext_vector_type(4))) float f32x4;

__device__ __forceinline__ unsigned short f2bf(float f) {
  union { float f; unsigned u; } v; v.f = f;
  unsigned r = (v.u + 0x7FFFu + ((v.u >> 16) & 1u)) >> 16;
  return (unsigned short)r;
}
__device__ __forceinline__ float sigm(float x) { return 1.0f / (1.0f + __expf(-x)); }
__device__ __forceinline__ float tanh_(float x) {
  float t = __expf(2.0f * x);
  return 1.0f - 2.0f / (t + 1.0f);
}

// Per-lane: acc (post-bias own-gate), gather other 3 gates via shfl_xor, update c, produce h.
__device__ __forceinline__ void cell_update(const f32x4& acc, float bias, int gate,
                                            float* cst, float* hv) {
  #pragma unroll
  for (int r = 0; r < 4; ++r) {
    float own = acc[r] + bias;
    float v4  = __shfl_xor(own, 4, 64);   // gate ^ 1
    float v8  = __shfl_xor(own, 8, 64);   // gate ^ 2
    float v12 = __shfl_xor(own, 12, 64);  // gate ^ 3
    float pi = gate==0?own : gate==1?v4 : gate==2?v8  : v12;
    float pf = gate==1?own : gate==0?v4 : gate==3?v8  : v12;
    float pg = gate==2?own : gate==3?v4 : gate==0?v8  : v12;
    float po = gate==3?own : gate==2?v4 : gate==1?v8  : v12;
    float iv = sigm(pi), fv = sigm(pf), gv = tanh_(pg), ov = sigm(po);
    cst[r] = fv * cst[r] + iv * gv;
    hv[r]  = ov * tanh_(cst[r]);
  }
}

// Pack 4 bf16 cols into u64 and store (lanes n==0 only). dst in u64 units.
__device__ __forceinline__ void store_h(const float* hv, unsigned long long* dst,
                                        int bb, int kgrp, int lane, int u64col) {
  #pragma unroll
  for (int r = 0; r < 4; ++r) {
    unsigned int hb  = f2bf(hv[r]);
    unsigned int p01 = hb | ((((unsigned)__shfl_xor((int)hb, 1, 64)) & 0xFFFFu) << 16);
    unsigned int p23 = (unsigned)__shfl_xor((int)p01, 2, 64);
    if ((lane & 15) == 0) {
      unsigned long long u = (unsigned long long)p01 | ((unsigned long long)p23 << 32);
      __hip_atomic_store(dst + (size_t)(bb + kgrp*4 + r) * (H_/4) + u64col, u,
                         __ATOMIC_RELAXED, __HIP_MEMORY_SCOPE_AGENT);
    }
  }
}

// Fused 2-layer LSTM, pipelined: super-step s does L0 step s and L1 step s-1.
// 4 batch-groups x 64 CUs; CU owns 8 h-cols; wave (p=w>>1, mt=w&1) owns
// cols [8c+4p,+4) x Mtile mt; B rows = gate*4+csub (all 4 gates per wave).
__global__ __launch_bounds__(256, 1)
void lstm_fused(const float* __restrict__ Wih0, const float* __restrict__ Whh0,
                const float* __restrict__ bih0, const float* __restrict__ bhh0,
                const float* __restrict__ Wih1, const float* __restrict__ Whh1,
                const float* __restrict__ bih1, const float* __restrict__ bhh1,
                const float* __restrict__ x,
                unsigned long long* __restrict__ hc1,   // [2][B][H/4] u64(bf16x4)
                unsigned long long* __restrict__ hc2,
                float* __restrict__ h2last,             // [B][H] f32
                unsigned int* __restrict__ cnts)        // 32 lines x 64B per group
{
  __shared__ unsigned short W0[2*16*512];   // [p][n][k] W_hh0, swizzled
  __shared__ unsigned short W1[2*16*512];   // W_hh1
  __shared__ unsigned short A1[32*512];     // h1[s-1], rows = batch-in-group
  __shared__ unsigned short A2[32*512];     // h2[s-2]

  const int tid  = threadIdx.x;
  const int w    = tid >> 6;
  const int lane = tid & 63;
  const int n    = lane & 15;
  const int kgrp = lane >> 4;
  const int p    = w >> 1;
  const int mt   = w & 1;
  const int g    = blockIdx.x >> 6;
  const int c    = blockIdx.x & 63;
  const int gate = n >> 2;
  const int col  = c*8 + p*4 + (n & 3);
  const int bb   = g*32 + mt*16;

  // ---- stage recurrent weights into LDS (once) ----
  for (int idx = tid; idx < 2*16*512; idx += 256) {
    int k  = idx & 511;
    int rn = idx >> 9;
    int nn = rn & 15;
    int pp = rn >> 4;
    int grow = (nn >> 2)*H_ + c*8 + pp*4 + (nn & 3);
    int byteoff = (idx*2) ^ ((nn & 7) << 4);
    *(unsigned short*)((char*)W0 + byteoff) = f2bf(Whh0[(size_t)grow*H_ + k]);
    *(unsigned short*)((char*)W1 + byteoff) = f2bf(Whh1[(size_t)grow*H_ + k]);
  }

  // ---- input-half weights in registers ----
  short8v breg1[16];                         // W_ih1 B-frags (K=512)
  #pragma unroll
  for (int kk = 0; kk < 16; ++kk)
    #pragma unroll
    for (int e = 0; e < 8; ++e)
      breg1[kk][e] = (short)f2bf(Wih1[(size_t)(gate*H_ + col)*H_ + kk*32 + kgrp*8 + e]);
  short8v bireg0[2];                         // W_ih0 B-frags (K=64)
  #pragma unroll
  for (int kk = 0; kk < 2; ++kk)
    #pragma unroll
    for (int e = 0; e < 8; ++e)
      bireg0[kk][e] = (short)f2bf(Wih0[(size_t)(gate*H_ + col)*I_ + kk*32 + kgrp*8 + e]);

  const float bias0 = bih0[gate*H_ + col] + bhh0[gate*H_ + col];
  const float bias1 = bih1[gate*H_ + col] + bhh1[gate*H_ + col];

  float c1[4] = {0.f,0.f,0.f,0.f}, c2[4] = {0.f,0.f,0.f,0.f};

  const float* xbase = x + (size_t)(bb + n) * T_ * I_;
  float xr[16];
  #pragma unroll
  for (int e = 0; e < 8; ++e) { xr[e] = xbase[kgrp*8 + e]; xr[8+e] = xbase[32 + kgrp*8 + e]; }

  const int srow = tid >> 3;                 // staging row 0..31
  const int t7   = tid & 7;
  unsigned int* cg = cnts + g*512;           // 32 lines/group, stride 16 u32 (64B)
  const int myline = ((c & 7)*4 + w) * 16;
  const int aswz  = (n & 7) << 4;
  const int abase = (mt*16 + n) * 1024;      // A row byte base
  const int bbase = (p*16 + n) * 1024;       // W row byte base
  const int u64col = c*2 + p;

  for (int s = 0; s <= T_; ++s) {
    // ---- stage A1 <- h1[s-1] (parity (s+1)&1), A2 <- h2[s-2] (parity s&1) ----
    {
      const unsigned long long* s1 = hc1 + (size_t)((s+1)&1)*(B_*H_/4) + (size_t)(g*32 + srow)*(H_/4);
      const unsigned long long* s2 = hc2 + (size_t)(s&1)*(B_*H_/4)     + (size_t)(g*32 + srow)*(H_/4);
      #pragma unroll
      for (int ch = 0; ch < 2; ++ch) {
        unsigned long long tmp[8];
        #pragma unroll
        for (int j = 0; j < 8; ++j)
          tmp[j] = __hip_atomic_load(s1 + (ch*8 + j)*8 + t7, __ATOMIC_RELAXED, __HIP_MEMORY_SCOPE_AGENT);
        #pragma unroll
        for (int j = 0; j < 8; ++j) {
          int q = ch*8 + j;
          int byteoff = (srow*1024 + (q*8 + t7)*8) ^ ((srow & 7) << 4);
          *(unsigned long long*)((char*)A1 + byteoff) = tmp[j];
        }
      }
      #pragma unroll
      for (int ch = 0; ch < 2; ++ch) {
        unsigned long long tmp[8];
        #pragma unroll
        for (int j = 0; j < 8; ++j)
          tmp[j] = __hip_atomic_load(s2 + (ch*8 + j)*8 + t7, __ATOMIC_RELAXED, __HIP_MEMORY_SCOPE_AGENT);
        #pragma unroll
        for (int j = 0; j < 8; ++j) {
          int q = ch*8 + j;
          int byteoff = (srow*1024 + (q*8 + t7)*8) ^ ((srow & 7) << 4);
          *(unsigned long long*)((char*)A2 + byteoff) = tmp[j];
        }
      }
    }
    __syncthreads();

    // ---- L0 step s: gates = [x_t | h1[s-1]] @ W0^T ----
    if (s < T_) {
      f32x4 acc = {0.f,0.f,0.f,0.f};
      #pragma unroll
      for (int kk = 0; kk < 2; ++kk) {
        short8v a;
        #pragma unroll
        for (int e = 0; e < 8; ++e) a[e] = (short)f2bf(xr[kk*8 + e]);
        acc = __builtin_amdgcn_mfma_f32_16x16x32_bf16(a, bireg0[kk], acc, 0, 0, 0);
      }
      #pragma unroll
      for (int kk = 0; kk < 16; ++kk) {
        short8v a = *(const short8v*)((const char*)A1 + ((abase + kk*64 + kgrp*16) ^ aswz));
        short8v b = *(const short8v*)((const char*)W0 + ((bbase + kk*64 + kgrp*16) ^ aswz));
        acc = __builtin_amdgcn_mfma_f32_16x16x32_bf16(a, b, acc, 0, 0, 0);
      }
      float hv[4];
      cell_update(acc, bias0, gate, c1, hv);
      store_h(hv, hc1 + (size_t)(s&1)*(B_*H_/4), bb, kgrp, lane, u64col);
    }

    // ---- L1 step s-1: gates = W_ih1·h1[s-1] + W_hh1·h2[s-2] ----
    if (s >= 1) {
      f32x4 acc = {0.f,0.f,0.f,0.f};
      #pragma unroll
      for (int kk = 0; kk < 16; ++kk) {
        short8v a = *(const short8v*)((const char*)A1 + ((abase + kk*64 + kgrp*16) ^ aswz));
        acc = __builtin_amdgcn_mfma_f32_16x16x32_bf16(a, breg1[kk], acc, 0, 0, 0);
      }
      #pragma unroll
      for (int kk = 0; kk < 16; ++kk) {
        short8v a = *(const short8v*)((const char*)A2 + ((abase + kk*64 + kgrp*16) ^ aswz));
        short8v b = *(const short8v*)((const char*)W1 + ((bbase + kk*64 + kgrp*16) ^ aswz));
        acc = __builtin_amdgcn_mfma_f32_16x16x32_bf16(a, b, acc, 0, 0, 0);
      }
      float hv[4];
      cell_update(acc, bias1, gate, c2, hv);
      if (s < T_) {
        store_h(hv, hc2 + (size_t)((s+1)&1)*(B_*H_/4), bb, kgrp, lane, u64col);
      } else if (gate == 0) {
        #pragma unroll
        for (int r = 0; r < 4; ++r)
          h2last[(size_t)(bb + kgrp*4 + r)*H_ + col] = hv[r];
      }
    }

    // ---- prefetch x for t=s+1 (hidden under store drain + spin) ----
    if (s + 1 < T_) {
      const float* xp = xbase + (size_t)(s+1)*I_;
      #pragma unroll
      for (int e = 0; e < 8; ++e) { xr[e] = xp[kgrp*8 + e]; xr[8+e] = xp[32 + kgrp*8 + e]; }
    }

    // ---- per-wave arrive (release) + group spin ----
    if (s < T_) {
      if (lane == 0) {
        __hip_atomic_fetch_add(cg + myline, 1u, __ATOMIC_RELEASE, __HIP_MEMORY_SCOPE_AGENT);
        const unsigned target = 256u * (unsigned)(s + 1);
        for (;;) {
          unsigned sum = 0;
          #pragma unroll
          for (int qq = 0; qq < 32; ++qq)
            sum += __hip_atomic_load(cg + qq*16, __ATOMIC_RELAXED, __HIP_MEMORY_SCOPE_AGENT);
          if (sum >= target) break;
        }
      }
      __builtin_amdgcn_fence(__ATOMIC_ACQUIRE, "agent");
    }
  }
}

__global__ void out_proj(const float* __restrict__ h2last,
                         const float* __restrict__ Wout,
                         const float* __restrict__ bout,
                         float* __restrict__ out) {
  int o = blockIdx.x;            // 0..383 = b*3+cc
  int b = o / 3, cc = o - b * 3;
  int ln = threadIdx.x;          // 64
  float s = 0.f;
  #pragma unroll
  for (int k = ln; k < H_; k += 64) s += h2last[b * H_ + k] * Wout[cc * H_ + k];
  #pragma unroll
  for (int off = 32; off; off >>= 1) s += __shfl_down(s, off, 64);
  if (ln == 0) out[o] = s + bout[cc];
}

extern "C" void kernel_launch(void* const* d_in, const int* in_sizes, int n_in,
                              void* d_out, int out_size, void* d_ws, size_t ws_size,
                              hipStream_t stream) {
  (void)in_sizes; (void)n_in; (void)out_size; (void)ws_size;
  const float* x    = (const float*)d_in[0];
  const float* Wih0 = (const float*)d_in[1];
  const float* Whh0 = (const float*)d_in[2];
  const float* bih0 = (const float*)d_in[3];
  const float* bhh0 = (const float*)d_in[4];
  const float* Wih1 = (const float*)d_in[5];
  const float* Whh1 = (const float*)d_in[6];
  const float* bih1 = (const float*)d_in[7];
  const float* bhh1 = (const float*)d_in[8];
  const float* Wout = (const float*)d_in[9];
  const float* bout = (const float*)d_in[10];

  char* ws = (char*)d_ws;
  unsigned long long* hc1 = (unsigned long long*)(ws);            // 262144 B
  unsigned long long* hc2 = (unsigned long long*)(ws + 262144);   // 262144 B
  unsigned int* cnts      = (unsigned int*)(ws + 524288);         // 8192 B
  float* h2last           = (float*)(ws + 532480);                // 262144 B

  // zero h ping-pongs (h_init = 0) + counters, every launch (deterministic replays)
  hipMemsetAsync(ws, 0, 532480, stream);

  void* args[12] = {
    (void*)&Wih0, (void*)&Whh0, (void*)&bih0, (void*)&bhh0,
    (void*)&Wih1, (void*)&Whh1, (void*)&bih1, (void*)&bhh1,
    (void*)&x, (void*)&hc1, (void*)&hc2, (void*)&h2last
  };
  void* args2[13] = {
    (void*)&Wih0, (void*)&Whh0, (void*)&bih0, (void*)&bhh0,
    (void*)&Wih1, (void*)&Whh1, (void*)&bih1, (void*)&bhh1,
    (void*)&x, (void*)&hc1, (void*)&hc2, (void*)&h2last, (void*)&cnts
  };
  (void)args;
  hipLaunchCooperativeKernel(reinterpret_cast<const void*>(&lstm_fused),
                             dim3(256), dim3(256), args2, 0, stream);
  out_proj<<<dim3(384), dim3(64), 0, stream>>>(h2last, Wout, bout, (float*)d_out);
}

// Round 6
// 12316.017 us; speedup vs baseline: 1.1392x; 1.1392x over previous
//
#include <hip/hip_runtime.h>
#include <hip/hip_bf16.h>
#include <cstddef>

#define B_ 128
#define T_ 512
#define I_ 64
#define H_ 512

typedef __attribute__((ext_vector_type(8))) short short8v;
typedef __attribute__((ext_vector_type(4))) float f32x4;

__device__ __forceinline__ unsigned short f2bf(float f) {
  union { float f; unsigned u; } v; v.f = f;
  unsigned r = (v.u + 0x7FFFu + ((v.u >> 16) & 1u)) >> 16;
  return (unsigned short)r;
}
__device__ __forceinline__ float sigm(float x) { return 1.0f / (1.0f + __expf(-x)); }
__device__ __forceinline__ float tanh_(float x) {
  float t = __expf(2.0f * x);
  return 1.0f - 2.0f / (t + 1.0f);
}

// Per-lane: acc (post-bias own-gate), gather other 3 gates via shfl_xor, update c, produce h.
__device__ __forceinline__ void cell_update(const f32x4& acc, float bias, int gate,
                                            float* cst, float* hv) {
  #pragma unroll
  for (int r = 0; r < 4; ++r) {
    float own = acc[r] + bias;
    float v4  = __shfl_xor(own, 4, 64);   // gate ^ 1
    float v8  = __shfl_xor(own, 8, 64);   // gate ^ 2
    float v12 = __shfl_xor(own, 12, 64);  // gate ^ 3
    float pi = gate==0?own : gate==1?v4 : gate==2?v8  : v12;
    float pf = gate==1?own : gate==0?v4 : gate==3?v8  : v12;
    float pg = gate==2?own : gate==3?v4 : gate==0?v8  : v12;
    float po = gate==3?own : gate==2?v4 : gate==1?v8  : v12;
    float iv = sigm(pi), fv = sigm(pf), gv = tanh_(pg), ov = sigm(po);
    cst[r] = fv * cst[r] + iv * gv;
    hv[r]  = ov * tanh_(cst[r]);
  }
}

// Pack 4 bf16 cols into u64 and store (lanes n==0 only). dst in u64 units.
__device__ __forceinline__ void store_h(const float* hv, unsigned long long* dst,
                                        int bb, int kgrp, int lane, int u64col) {
  #pragma unroll
  for (int r = 0; r < 4; ++r) {
    unsigned int hb  = f2bf(hv[r]);
    unsigned int p01 = hb | ((((unsigned)__shfl_xor((int)hb, 1, 64)) & 0xFFFFu) << 16);
    unsigned int p23 = (unsigned)__shfl_xor((int)p01, 2, 64);
    if ((lane & 15) == 0) {
      unsigned long long u = (unsigned long long)p01 | ((unsigned long long)p23 << 32);
      __hip_atomic_store(dst + (size_t)(bb + kgrp*4 + r) * (H_/4) + u64col, u,
                         __ATOMIC_RELAXED, __HIP_MEMORY_SCOPE_AGENT);
    }
  }
}

// Fused 2-layer LSTM, pipelined: super-step s does L0 step s and L1 step s-1.
// 4 batch-groups x 64 CUs; CU owns 8 h-cols. Barrier = round-2's proven flat
// scheme (per-wave release arrive to 32 lines; poller sums all 32 + acquire
// fence) with two safe edits: only wave 0 polls (others park in syncthreads)
// and s_sleep(1) backoff between sweeps.
__global__ __launch_bounds__(256, 1)
void lstm_fused(const float* __restrict__ Wih0, const float* __restrict__ Whh0,
                const float* __restrict__ bih0, const float* __restrict__ bhh0,
                const float* __restrict__ Wih1, const float* __restrict__ Whh1,
                const float* __restrict__ bih1, const float* __restrict__ bhh1,
                const float* __restrict__ x,
                unsigned long long* __restrict__ hc1,   // [2][B][H/4] u64(bf16x4)
                unsigned long long* __restrict__ hc2,
                float* __restrict__ h2last,             // [B][H] f32
                unsigned int* __restrict__ cnts)        // 32 lines x 64B per group
{
  __shared__ unsigned short W0[2*16*512];   // [p][n][k] W_hh0, swizzled
  __shared__ unsigned short W1[2*16*512];   // W_hh1
  __shared__ unsigned short A1[32*512];     // h1[s-1]
  __shared__ unsigned short A2[32*512];     // h2[s-2]

  const int tid  = threadIdx.x;
  const int w    = tid >> 6;
  const int lane = tid & 63;
  const int n    = lane & 15;
  const int kgrp = lane >> 4;
  const int p    = w >> 1;
  const int mt   = w & 1;
  const int g    = blockIdx.x >> 6;
  const int c    = blockIdx.x & 63;
  const int gate = n >> 2;
  const int col  = c*8 + p*4 + (n & 3);
  const int bb   = g*32 + mt*16;

  // ---- stage recurrent weights into LDS (once) ----
  for (int idx = tid; idx < 2*16*512; idx += 256) {
    int k  = idx & 511;
    int rn = idx >> 9;
    int nn = rn & 15;
    int pp = rn >> 4;
    int grow = (nn >> 2)*H_ + c*8 + pp*4 + (nn & 3);
    int byteoff = (idx*2) ^ ((nn & 7) << 4);
    *(unsigned short*)((char*)W0 + byteoff) = f2bf(Whh0[(size_t)grow*H_ + k]);
    *(unsigned short*)((char*)W1 + byteoff) = f2bf(Whh1[(size_t)grow*H_ + k]);
  }

  // ---- input-half weights in registers ----
  short8v breg1[16];                         // W_ih1 B-frags (K=512)
  #pragma unroll
  for (int kk = 0; kk < 16; ++kk)
    #pragma unroll
    for (int e = 0; e < 8; ++e)
      breg1[kk][e] = (short)f2bf(Wih1[(size_t)(gate*H_ + col)*H_ + kk*32 + kgrp*8 + e]);
  short8v bireg0[2];                         // W_ih0 B-frags (K=64)
  #pragma unroll
  for (int kk = 0; kk < 2; ++kk)
    #pragma unroll
    for (int e = 0; e < 8; ++e)
      bireg0[kk][e] = (short)f2bf(Wih0[(size_t)(gate*H_ + col)*I_ + kk*32 + kgrp*8 + e]);

  const float bias0 = bih0[gate*H_ + col] + bhh0[gate*H_ + col];
  const float bias1 = bih1[gate*H_ + col] + bhh1[gate*H_ + col];

  float c1[4] = {0.f,0.f,0.f,0.f}, c2[4] = {0.f,0.f,0.f,0.f};

  const float* xbase = x + (size_t)(bb + n) * T_ * I_;
  float xr[16];
  #pragma unroll
  for (int e = 0; e < 8; ++e) { xr[e] = xbase[kgrp*8 + e]; xr[8+e] = xbase[32 + kgrp*8 + e]; }

  const int srow = tid >> 3;                 // staging row 0..31
  const int t7   = tid & 7;
  unsigned int* cg = cnts + g*512;           // 32 lines/group, stride 16 u32 (64B)
  const int myline = ((c & 7)*4 + w) * 16;
  const int aswz  = (n & 7) << 4;
  const int abase = (mt*16 + n) * 1024;      // A row byte base
  const int bbase = (p*16 + n) * 1024;       // W row byte base
  const int u64col = c*2 + p;

  for (int s = 0; s <= T_; ++s) {
    // ---- stage A1 <- h1[s-1] (parity (s+1)&1), A2 <- h2[s-2] (parity s&1) ----
    {
      const unsigned long long* s1 = hc1 + (size_t)((s+1)&1)*(B_*H_/4) + (size_t)(g*32 + srow)*(H_/4);
      const unsigned long long* s2 = hc2 + (size_t)(s&1)*(B_*H_/4)     + (size_t)(g*32 + srow)*(H_/4);
      #pragma unroll
      for (int ch = 0; ch < 2; ++ch) {
        unsigned long long tmp[8];
        #pragma unroll
        for (int j = 0; j < 8; ++j)
          tmp[j] = __hip_atomic_load(s1 + (ch*8 + j)*8 + t7, __ATOMIC_RELAXED, __HIP_MEMORY_SCOPE_AGENT);
        #pragma unroll
        for (int j = 0; j < 8; ++j) {
          int q = ch*8 + j;
          int byteoff = (srow*1024 + (q*8 + t7)*8) ^ ((srow & 7) << 4);
          *(unsigned long long*)((char*)A1 + byteoff) = tmp[j];
        }
      }
      #pragma unroll
      for (int ch = 0; ch < 2; ++ch) {
        unsigned long long tmp[8];
        #pragma unroll
        for (int j = 0; j < 8; ++j)
          tmp[j] = __hip_atomic_load(s2 + (ch*8 + j)*8 + t7, __ATOMIC_RELAXED, __HIP_MEMORY_SCOPE_AGENT);
        #pragma unroll
        for (int j = 0; j < 8; ++j) {
          int q = ch*8 + j;
          int byteoff = (srow*1024 + (q*8 + t7)*8) ^ ((srow & 7) << 4);
          *(unsigned long long*)((char*)A2 + byteoff) = tmp[j];
        }
      }
    }
    __syncthreads();

    // ---- L0 step s: gates = [x_t | h1[s-1]] @ W0^T ----
    if (s < T_) {
      f32x4 acc = {0.f,0.f,0.f,0.f};
      #pragma unroll
      for (int kk = 0; kk < 2; ++kk) {
        short8v a;
        #pragma unroll
        for (int e = 0; e < 8; ++e) a[e] = (short)f2bf(xr[kk*8 + e]);
        acc = __builtin_amdgcn_mfma_f32_16x16x32_bf16(a, bireg0[kk], acc, 0, 0, 0);
      }
      #pragma unroll
      for (int kk = 0; kk < 16; ++kk) {
        short8v a = *(const short8v*)((const char*)A1 + ((abase + kk*64 + kgrp*16) ^ aswz));
        short8v b = *(const short8v*)((const char*)W0 + ((bbase + kk*64 + kgrp*16) ^ aswz));
        acc = __builtin_amdgcn_mfma_f32_16x16x32_bf16(a, b, acc, 0, 0, 0);
      }
      float hv[4];
      cell_update(acc, bias0, gate, c1, hv);
      store_h(hv, hc1 + (size_t)(s&1)*(B_*H_/4), bb, kgrp, lane, u64col);
    }

    // ---- L1 step s-1: gates = W_ih1·h1[s-1] + W_hh1·h2[s-2] ----
    if (s >= 1) {
      f32x4 acc = {0.f,0.f,0.f,0.f};
      #pragma unroll
      for (int kk = 0; kk < 16; ++kk) {
        short8v a = *(const short8v*)((const char*)A1 + ((abase + kk*64 + kgrp*16) ^ aswz));
        acc = __builtin_amdgcn_mfma_f32_16x16x32_bf16(a, breg1[kk], acc, 0, 0, 0);
      }
      #pragma unroll
      for (int kk = 0; kk < 16; ++kk) {
        short8v a = *(const short8v*)((const char*)A2 + ((abase + kk*64 + kgrp*16) ^ aswz));
        short8v b = *(const short8v*)((const char*)W1 + ((bbase + kk*64 + kgrp*16) ^ aswz));
        acc = __builtin_amdgcn_mfma_f32_16x16x32_bf16(a, b, acc, 0, 0, 0);
      }
      float hv[4];
      cell_update(acc, bias1, gate, c2, hv);
      if (s < T_) {
        store_h(hv, hc2 + (size_t)((s+1)&1)*(B_*H_/4), bb, kgrp, lane, u64col);
      } else if (gate == 0) {
        #pragma unroll
        for (int r = 0; r < 4; ++r)
          h2last[(size_t)(bb + kgrp*4 + r)*H_ + col] = hv[r];
      }
    }

    if (s < T_) {
      // ---- arrive: per-wave release add (orders this wave's h-stores) ----
      if (lane == 0)
        __hip_atomic_fetch_add(cg + myline, 1u, __ATOMIC_RELEASE, __HIP_MEMORY_SCOPE_AGENT);

      // ---- prefetch x for t=s+1 (overlaps other CUs' arrivals) ----
      if (s + 1 < T_) {
        const float* xp = xbase + (size_t)(s+1)*I_;
        #pragma unroll
        for (int e = 0; e < 8; ++e) { xr[e] = xp[kgrp*8 + e]; xr[8+e] = xp[32 + kgrp*8 + e]; }
      }

      // ---- wait: wave 0 spin-sums all 32 lines (with backoff); others park ----
      if (w == 0 && lane == 0) {
        const unsigned target = 256u * (unsigned)(s + 1);
        for (;;) {
          unsigned sum = 0;
          #pragma unroll
          for (int qq = 0; qq < 32; ++qq)
            sum += __hip_atomic_load(cg + qq*16, __ATOMIC_RELAXED, __HIP_MEMORY_SCOPE_AGENT);
          if (sum >= target) break;
          __builtin_amdgcn_s_sleep(1);
        }
      }
      // wave0: acquire after observing all releases; syncthreads propagates
      // happens-before to waves 1-3 before they stage next step.
      __builtin_amdgcn_fence(__ATOMIC_ACQUIRE, "agent");
      __syncthreads();
    }
  }
}

__global__ void out_proj(const float* __restrict__ h2last,
                         const float* __restrict__ Wout,
                         const float* __restrict__ bout,
                         float* __restrict__ out) {
  int o = blockIdx.x;            // 0..383 = b*3+cc
  int b = o / 3, cc = o - b * 3;
  int ln = threadIdx.x;          // 64
  float s = 0.f;
  #pragma unroll
  for (int k = ln; k < H_; k += 64) s += h2last[b * H_ + k] * Wout[cc * H_ + k];
  #pragma unroll
  for (int off = 32; off; off >>= 1) s += __shfl_down(s, off, 64);
  if (ln == 0) out[o] = s + bout[cc];
}

extern "C" void kernel_launch(void* const* d_in, const int* in_sizes, int n_in,
                              void* d_out, int out_size, void* d_ws, size_t ws_size,
                              hipStream_t stream) {
  (void)in_sizes; (void)n_in; (void)out_size; (void)ws_size;
  const float* x    = (const float*)d_in[0];
  const float* Wih0 = (const float*)d_in[1];
  const float* Whh0 = (const float*)d_in[2];
  const float* bih0 = (const float*)d_in[3];
  const float* bhh0 = (const float*)d_in[4];
  const float* Wih1 = (const float*)d_in[5];
  const float* Whh1 = (const float*)d_in[6];
  const float* bih1 = (const float*)d_in[7];
  const float* bhh1 = (const float*)d_in[8];
  const float* Wout = (const float*)d_in[9];
  const float* bout = (const float*)d_in[10];

  char* ws = (char*)d_ws;
  unsigned long long* hc1 = (unsigned long long*)(ws);            // 262144 B
  unsigned long long* hc2 = (unsigned long long*)(ws + 262144);   // 262144 B
  unsigned int* cnts      = (unsigned int*)(ws + 524288);         // 8192 B (4 groups x 2KB)
  float* h2last           = (float*)(ws + 532480);                // 262144 B

  // zero h ping-pongs (h_init = 0) + barrier counters, every launch
  hipMemsetAsync(ws, 0, 532480, stream);

  void* args[13] = {
    (void*)&Wih0, (void*)&Whh0, (void*)&bih0, (void*)&bhh0,
    (void*)&Wih1, (void*)&Whh1, (void*)&bih1, (void*)&bhh1,
    (void*)&x, (void*)&hc1, (void*)&hc2, (void*)&h2last, (void*)&cnts
  };
  hipLaunchCooperativeKernel(reinterpret_cast<const void*>(&lstm_fused),
                             dim3(256), dim3(256), args, 0, stream);
  out_proj<<<dim3(384), dim3(64), 0, stream>>>(h2last, Wout, bout, (float*)d_out);
}

// Round 8
// 12135.951 us; speedup vs baseline: 1.1561x; 1.0148x over previous
//
#include <hip/hip_runtime.h>
#include <hip/hip_bf16.h>
#include <cstddef>

#define B_ 128
#define T_ 512
#define I_ 64
#define H_ 512

typedef __attribute__((ext_vector_type(8))) short short8v;
typedef __attribute__((ext_vector_type(4))) float f32x4;

__device__ __forceinline__ unsigned short f2bf(float f) {
  union { float f; unsigned u; } v; v.f = f;
  unsigned r = (v.u + 0x7FFFu + ((v.u >> 16) & 1u)) >> 16;
  return (unsigned short)r;
}
__device__ __forceinline__ float sigm(float x) { return 1.0f / (1.0f + __expf(-x)); }
__device__ __forceinline__ float tanh_(float x) {
  float t = __expf(2.0f * x);
  return 1.0f - 2.0f / (t + 1.0f);
}

// Per-lane: acc (post-bias own-gate), gather other 3 gates via shfl_xor, update c, produce h.
__device__ __forceinline__ void cell_update(const f32x4& acc, float bias, int gate,
                                            float* cst, float* hv) {
  #pragma unroll
  for (int r = 0; r < 4; ++r) {
    float own = acc[r] + bias;
    float v4  = __shfl_xor(own, 4, 64);   // gate ^ 1
    float v8  = __shfl_xor(own, 8, 64);   // gate ^ 2
    float v12 = __shfl_xor(own, 12, 64);  // gate ^ 3
    float pi = gate==0?own : gate==1?v4 : gate==2?v8  : v12;
    float pf = gate==1?own : gate==0?v4 : gate==3?v8  : v12;
    float pg = gate==2?own : gate==3?v4 : gate==0?v8  : v12;
    float po = gate==3?own : gate==2?v4 : gate==1?v8  : v12;
    float iv = sigm(pi), fv = sigm(pf), gv = tanh_(pg), ov = sigm(po);
    cst[r] = fv * cst[r] + iv * gv;
    hv[r]  = ov * tanh_(cst[r]);
  }
}

// Pack 4 bf16 cols into u64 and store (lanes n==0 only). dst in u64 units.
__device__ __forceinline__ void store_h(const float* hv, unsigned long long* dst,
                                        int bb, int kgrp, int lane, int u64col) {
  #pragma unroll
  for (int r = 0; r < 4; ++r) {
    unsigned int hb  = f2bf(hv[r]);
    unsigned int p01 = hb | ((((unsigned)__shfl_xor((int)hb, 1, 64)) & 0xFFFFu) << 16);
    unsigned int p23 = (unsigned)__shfl_xor((int)p01, 2, 64);
    if ((lane & 15) == 0) {
      unsigned long long u = (unsigned long long)p01 | ((unsigned long long)p23 << 32);
      __hip_atomic_store(dst + (size_t)(bb + kgrp*4 + r) * (H_/4) + u64col, u,
                         __ATOMIC_RELAXED, __HIP_MEMORY_SCOPE_AGENT);
    }
  }
}

// Fused 2-layer LSTM, pipelined: super-step s does L0 step s and L1 step s-1.
// 4 batch-groups x 64 CUs; CU owns 8 h-cols. Staging/arrive = round-6 verbatim
// (tmp[8] chunks — low register pressure; 64-reg batches correlate with the
// 0.157 launch-failure signature). ONLY change vs round 6: wave-parallel
// barrier sweep (lane i of wave 0 loads line i concurrently, butterfly sum,
// lane-0 broadcast for uniform exit) instead of lane0's 32 serialized loads.
__global__ __launch_bounds__(256, 1)
void lstm_fused(const float* __restrict__ Wih0, const float* __restrict__ Whh0,
                const float* __restrict__ bih0, const float* __restrict__ bhh0,
                const float* __restrict__ Wih1, const float* __restrict__ Whh1,
                const float* __restrict__ bih1, const float* __restrict__ bhh1,
                const float* __restrict__ x,
                unsigned long long* __restrict__ hc1,   // [2][B][H/4] u64(bf16x4)
                unsigned long long* __restrict__ hc2,
                float* __restrict__ h2last,             // [B][H] f32
                unsigned int* __restrict__ cnts)        // 32 lines x 64B per group
{
  __shared__ unsigned short W0[2*16*512];   // [p][n][k] W_hh0, swizzled
  __shared__ unsigned short W1[2*16*512];   // W_hh1
  __shared__ unsigned short A1[32*512];     // h1[s-1]
  __shared__ unsigned short A2[32*512];     // h2[s-2]

  const int tid  = threadIdx.x;
  const int w    = tid >> 6;
  const int lane = tid & 63;
  const int n    = lane & 15;
  const int kgrp = lane >> 4;
  const int p    = w >> 1;
  const int mt   = w & 1;
  const int g    = blockIdx.x >> 6;
  const int c    = blockIdx.x & 63;
  const int gate = n >> 2;
  const int col  = c*8 + p*4 + (n & 3);
  const int bb   = g*32 + mt*16;

  // ---- stage recurrent weights into LDS (once) ----
  for (int idx = tid; idx < 2*16*512; idx += 256) {
    int k  = idx & 511;
    int rn = idx >> 9;
    int nn = rn & 15;
    int pp = rn >> 4;
    int grow = (nn >> 2)*H_ + c*8 + pp*4 + (nn & 3);
    int byteoff = (idx*2) ^ ((nn & 7) << 4);
    *(unsigned short*)((char*)W0 + byteoff) = f2bf(Whh0[(size_t)grow*H_ + k]);
    *(unsigned short*)((char*)W1 + byteoff) = f2bf(Whh1[(size_t)grow*H_ + k]);
  }

  // ---- input-half weights in registers ----
  short8v breg1[16];                         // W_ih1 B-frags (K=512)
  #pragma unroll
  for (int kk = 0; kk < 16; ++kk)
    #pragma unroll
    for (int e = 0; e < 8; ++e)
      breg1[kk][e] = (short)f2bf(Wih1[(size_t)(gate*H_ + col)*H_ + kk*32 + kgrp*8 + e]);
  short8v bireg0[2];                         // W_ih0 B-frags (K=64)
  #pragma unroll
  for (int kk = 0; kk < 2; ++kk)
    #pragma unroll
    for (int e = 0; e < 8; ++e)
      bireg0[kk][e] = (short)f2bf(Wih0[(size_t)(gate*H_ + col)*I_ + kk*32 + kgrp*8 + e]);

  const float bias0 = bih0[gate*H_ + col] + bhh0[gate*H_ + col];
  const float bias1 = bih1[gate*H_ + col] + bhh1[gate*H_ + col];

  float c1[4] = {0.f,0.f,0.f,0.f}, c2[4] = {0.f,0.f,0.f,0.f};

  const float* xbase = x + (size_t)(bb + n) * T_ * I_;
  float xr[16];
  #pragma unroll
  for (int e = 0; e < 8; ++e) { xr[e] = xbase[kgrp*8 + e]; xr[8+e] = xbase[32 + kgrp*8 + e]; }

  const int srow = tid >> 3;                 // staging row 0..31
  const int t7   = tid & 7;
  unsigned int* cg = cnts + g*512;           // 32 lines/group, stride 16 u32 (64B)
  const int myline = ((c & 7)*4 + w) * 16;
  const int aswz  = (n & 7) << 4;
  const int abase = (mt*16 + n) * 1024;      // A row byte base
  const int bbase = (p*16 + n) * 1024;       // W row byte base
  const int u64col = c*2 + p;

  for (int s = 0; s <= T_; ++s) {
    // ---- stage A1 <- h1[s-1] (parity (s+1)&1), A2 <- h2[s-2] (parity s&1) ----
    {
      const unsigned long long* s1 = hc1 + (size_t)((s+1)&1)*(B_*H_/4) + (size_t)(g*32 + srow)*(H_/4);
      const unsigned long long* s2 = hc2 + (size_t)(s&1)*(B_*H_/4)     + (size_t)(g*32 + srow)*(H_/4);
      #pragma unroll
      for (int ch = 0; ch < 2; ++ch) {
        unsigned long long tmp[8];
        #pragma unroll
        for (int j = 0; j < 8; ++j)
          tmp[j] = __hip_atomic_load(s1 + (ch*8 + j)*8 + t7, __ATOMIC_RELAXED, __HIP_MEMORY_SCOPE_AGENT);
        #pragma unroll
        for (int j = 0; j < 8; ++j) {
          int q = ch*8 + j;
          int byteoff = (srow*1024 + (q*8 + t7)*8) ^ ((srow & 7) << 4);
          *(unsigned long long*)((char*)A1 + byteoff) = tmp[j];
        }
      }
      #pragma unroll
      for (int ch = 0; ch < 2; ++ch) {
        unsigned long long tmp[8];
        #pragma unroll
        for (int j = 0; j < 8; ++j)
          tmp[j] = __hip_atomic_load(s2 + (ch*8 + j)*8 + t7, __ATOMIC_RELAXED, __HIP_MEMORY_SCOPE_AGENT);
        #pragma unroll
        for (int j = 0; j < 8; ++j) {
          int q = ch*8 + j;
          int byteoff = (srow*1024 + (q*8 + t7)*8) ^ ((srow & 7) << 4);
          *(unsigned long long*)((char*)A2 + byteoff) = tmp[j];
        }
      }
    }
    __syncthreads();

    // ---- L0 step s: gates = [x_t | h1[s-1]] @ W0^T ----
    if (s < T_) {
      f32x4 acc = {0.f,0.f,0.f,0.f};
      #pragma unroll
      for (int kk = 0; kk < 2; ++kk) {
        short8v a;
        #pragma unroll
        for (int e = 0; e < 8; ++e) a[e] = (short)f2bf(xr[kk*8 + e]);
        acc = __builtin_amdgcn_mfma_f32_16x16x32_bf16(a, bireg0[kk], acc, 0, 0, 0);
      }
      #pragma unroll
      for (int kk = 0; kk < 16; ++kk) {
        short8v a = *(const short8v*)((const char*)A1 + ((abase + kk*64 + kgrp*16) ^ aswz));
        short8v b = *(const short8v*)((const char*)W0 + ((bbase + kk*64 + kgrp*16) ^ aswz));
        acc = __builtin_amdgcn_mfma_f32_16x16x32_bf16(a, b, acc, 0, 0, 0);
      }
      float hv[4];
      cell_update(acc, bias0, gate, c1, hv);
      store_h(hv, hc1 + (size_t)(s&1)*(B_*H_/4), bb, kgrp, lane, u64col);
    }

    // ---- L1 step s-1: gates = W_ih1·h1[s-1] + W_hh1·h2[s-2] ----
    if (s >= 1) {
      f32x4 acc = {0.f,0.f,0.f,0.f};
      #pragma unroll
      for (int kk = 0; kk < 16; ++kk) {
        short8v a = *(const short8v*)((const char*)A1 + ((abase + kk*64 + kgrp*16) ^ aswz));
        acc = __builtin_amdgcn_mfma_f32_16x16x32_bf16(a, breg1[kk], acc, 0, 0, 0);
      }
      #pragma unroll
      for (int kk = 0; kk < 16; ++kk) {
        short8v a = *(const short8v*)((const char*)A2 + ((abase + kk*64 + kgrp*16) ^ aswz));
        short8v b = *(const short8v*)((const char*)W1 + ((bbase + kk*64 + kgrp*16) ^ aswz));
        acc = __builtin_amdgcn_mfma_f32_16x16x32_bf16(a, b, acc, 0, 0, 0);
      }
      float hv[4];
      cell_update(acc, bias1, gate, c2, hv);
      if (s < T_) {
        store_h(hv, hc2 + (size_t)((s+1)&1)*(B_*H_/4), bb, kgrp, lane, u64col);
      } else if (gate == 0) {
        #pragma unroll
        for (int r = 0; r < 4; ++r)
          h2last[(size_t)(bb + kgrp*4 + r)*H_ + col] = hv[r];
      }
    }

    if (s < T_) {
      // ---- arrive: per-wave release add (orders this wave's h-stores) ----
      if (lane == 0)
        __hip_atomic_fetch_add(cg + myline, 1u, __ATOMIC_RELEASE, __HIP_MEMORY_SCOPE_AGENT);

      // ---- prefetch x for t=s+1 (overlaps other CUs' arrivals) ----
      if (s + 1 < T_) {
        const float* xp = xbase + (size_t)(s+1)*I_;
        #pragma unroll
        for (int e = 0; e < 8; ++e) { xr[e] = xp[kgrp*8 + e]; xr[8+e] = xp[32 + kgrp*8 + e]; }
      }

      // ---- wait: wave 0 sweeps the 32 lines in parallel (lane i -> line i) ----
      if (w == 0) {
        const unsigned target = 256u * (unsigned)(s + 1);
        for (;;) {
          unsigned v = 0;
          if (lane < 32)
            v = __hip_atomic_load(cg + lane*16, __ATOMIC_RELAXED, __HIP_MEMORY_SCOPE_AGENT);
          #pragma unroll
          for (int off = 16; off; off >>= 1) v += (unsigned)__shfl_xor((int)v, off, 64);
          unsigned total = (unsigned)__shfl((int)v, 0, 64);   // uniform exit
          if (total >= target) break;
          __builtin_amdgcn_s_sleep(1);
        }
      }
      // polling lanes acquire their lines' release sequences; syncthreads
      // propagates happens-before to waves 1-3 before next staging.
      __builtin_amdgcn_fence(__ATOMIC_ACQUIRE, "agent");
      __syncthreads();
    }
  }
}

__global__ void out_proj(const float* __restrict__ h2last,
                         const float* __restrict__ Wout,
                         const float* __restrict__ bout,
                         float* __restrict__ out) {
  int o = blockIdx.x;            // 0..383 = b*3+cc
  int b = o / 3, cc = o - b * 3;
  int ln = threadIdx.x;          // 64
  float s = 0.f;
  #pragma unroll
  for (int k = ln; k < H_; k += 64) s += h2last[b * H_ + k] * Wout[cc * H_ + k];
  #pragma unroll
  for (int off = 32; off; off >>= 1) s += __shfl_down(s, off, 64);
  if (ln == 0) out[o] = s + bout[cc];
}

extern "C" void kernel_launch(void* const* d_in, const int* in_sizes, int n_in,
                              void* d_out, int out_size, void* d_ws, size_t ws_size,
                              hipStream_t stream) {
  (void)in_sizes; (void)n_in; (void)out_size; (void)ws_size;
  const float* x    = (const float*)d_in[0];
  const float* Wih0 = (const float*)d_in[1];
  const float* Whh0 = (const float*)d_in[2];
  const float* bih0 = (const float*)d_in[3];
  const float* bhh0 = (const float*)d_in[4];
  const float* Wih1 = (const float*)d_in[5];
  const float* Whh1 = (const float*)d_in[6];
  const float* bih1 = (const float*)d_in[7];
  const float* bhh1 = (const float*)d_in[8];
  const float* Wout = (const float*)d_in[9];
  const float* bout = (const float*)d_in[10];

  char* ws = (char*)d_ws;
  unsigned long long* hc1 = (unsigned long long*)(ws);            // 262144 B
  unsigned long long* hc2 = (unsigned long long*)(ws + 262144);   // 262144 B
  unsigned int* cnts      = (unsigned int*)(ws + 524288);         // 8192 B (4 groups x 2KB)
  float* h2last           = (float*)(ws + 532480);                // 262144 B

  // zero h ping-pongs (h_init = 0) + barrier counters, every launch
  hipMemsetAsync(ws, 0, 532480, stream);

  void* args[13] = {
    (void*)&Wih0, (void*)&Whh0, (void*)&bih0, (void*)&bhh0,
    (void*)&Wih1, (void*)&Whh1, (void*)&bih1, (void*)&bhh1,
    (void*)&x, (void*)&hc1, (void*)&hc2, (void*)&h2last, (void*)&cnts
  };
  hipLaunchCooperativeKernel(reinterpret_cast<const void*>(&lstm_fused),
                             dim3(256), dim3(256), args, 0, stream);
  out_proj<<<dim3(384), dim3(64), 0, stream>>>(h2last, Wout, bout, (float*)d_out);
}

// Round 10
// 10656.319 us; speedup vs baseline: 1.3166x; 1.1389x over previous
//
#include <hip/hip_runtime.h>
#include <hip/hip_bf16.h>
#include <cstddef>

#define B_ 128
#define T_ 512
#define I_ 64
#define H_ 512

typedef __attribute__((ext_vector_type(8))) short short8v;
typedef __attribute__((ext_vector_type(4))) float f32x4;

__device__ __forceinline__ unsigned short f2bf(float f) {
  union { float f; unsigned u; } v; v.f = f;
  unsigned r = (v.u + 0x7FFFu + ((v.u >> 16) & 1u)) >> 16;
  return (unsigned short)r;
}
__device__ __forceinline__ float sigm(float x) { return 1.0f / (1.0f + __expf(-x)); }
__device__ __forceinline__ float tanh_(float x) {
  float t = __expf(2.0f * x);
  return 1.0f - 2.0f / (t + 1.0f);
}

// acc row=kgrp*4+r (batch), col index n = gate*4+colsub. Gather the other 3
// gates via shfl_xor(4/8/12), update c, produce h. (R6/R8-proven.)
__device__ __forceinline__ void cell_update(const f32x4& acc, float bias, int gate,
                                            float* cst, float* hv) {
  #pragma unroll
  for (int r = 0; r < 4; ++r) {
    float own = acc[r] + bias;
    float v4  = __shfl_xor(own, 4, 64);
    float v8  = __shfl_xor(own, 8, 64);
    float v12 = __shfl_xor(own, 12, 64);
    float pi = gate==0?own : gate==1?v4 : gate==2?v8  : v12;
    float pf = gate==1?own : gate==0?v4 : gate==3?v8  : v12;
    float pg = gate==2?own : gate==3?v4 : gate==0?v8  : v12;
    float po = gate==3?own : gate==2?v4 : gate==1?v8  : v12;
    float iv = sigm(pi), fv = sigm(pf), gv = tanh_(pg), ov = sigm(po);
    cst[r] = fv * cst[r] + iv * gv;
    hv[r]  = ov * tanh_(cst[r]);
  }
}

// Pack 4 bf16 cols into u64, agent-scope store (lanes n==0). dst in u64 units.
__device__ __forceinline__ void store_h(const float* hv, unsigned long long* dst,
                                        int bb, int kgrp, int lane, int u64col) {
  #pragma unroll
  for (int r = 0; r < 4; ++r) {
    unsigned hb  = f2bf(hv[r]);
    unsigned p01 = hb | ((((unsigned)__shfl_xor((int)hb, 1, 64)) & 0xFFFFu) << 16);
    unsigned p23 = (unsigned)__shfl_xor((int)p01, 2, 64);
    if ((lane & 15) == 0) {
      unsigned long long u = (unsigned long long)p01 | ((unsigned long long)p23 << 32);
      __hip_atomic_store(dst + (size_t)(bb + kgrp*4 + r) * (H_/4) + u64col, u,
                         __ATOMIC_RELAXED, __HIP_MEMORY_SCOPE_AGENT);
    }
  }
}

// Fused 2-layer LSTM, pipelined: super-step s = L0 step s + L1 step s-1.
// 8 batch-groups x 32 CUs; CU owns 16 h-cols (wave p = col quad). Staging:
// one 8-deep tmp batch per buffer (1 LLC RT); A2 staged between L0 and L1 so
// its latency hides under L0. Barrier: R8's proven per-wave release arrive +
// wave-parallel sweep, agent scope throughout, bounded poll guard.
__global__ __launch_bounds__(256, 1)
void lstm_fused(const float* __restrict__ Wih0, const float* __restrict__ Whh0,
                const float* __restrict__ bih0, const float* __restrict__ bhh0,
                const float* __restrict__ Wih1, const float* __restrict__ Whh1,
                const float* __restrict__ bih1, const float* __restrict__ bhh1,
                const float* __restrict__ x,
                unsigned long long* __restrict__ hc1,   // [2][B][H/4] u64(bf16x4)
                unsigned long long* __restrict__ hc2,
                float* __restrict__ h2last,             // [B][H] f32
                unsigned int* __restrict__ cnts)        // 8 groups x 32 lines x 64B
{
  __shared__ unsigned short W0[4*16*512];   // Whh0 [p][n][k] swizzled (64 KB)
  __shared__ unsigned short W1[4*16*512];   // Whh1 (64 KB)
  __shared__ unsigned short A1[16*512];     // h1[s-1] (16 KB)
  __shared__ unsigned short A2[16*512];     // h2[s-2] (16 KB)  -> 160 KiB

  const int tid  = threadIdx.x;
  const int w    = tid >> 6;
  const int lane = tid & 63;
  const int n    = lane & 15;
  const int kgrp = lane >> 4;
  const int p    = w;                        // col quad 0..3
  const int g    = blockIdx.x >> 5;          // 8 groups
  const int c    = blockIdx.x & 31;          // 32 CUs/group
  const int gate = n >> 2;
  const int col  = c*16 + p*4 + (n & 3);
  const int bb   = g*16;

  // ---- stage recurrent weights into LDS (once) ----
  for (int idx = tid; idx < 4*16*512; idx += 256) {
    int k  = idx & 511;
    int rn = idx >> 9;                       // p*16+n
    int nn = rn & 15;
    int pp = rn >> 4;
    int grow = (nn >> 2)*H_ + c*16 + pp*4 + (nn & 3);
    int byteoff = (idx*2) ^ ((nn & 7) << 4);
    *(unsigned short*)((char*)W0 + byteoff) = f2bf(Whh0[(size_t)grow*H_ + k]);
    *(unsigned short*)((char*)W1 + byteoff) = f2bf(Whh1[(size_t)grow*H_ + k]);
  }

  // ---- input-half weights in registers ----
  short8v breg1[16];                         // Wih1 B-frags (K=512)
  #pragma unroll
  for (int kk = 0; kk < 16; ++kk)
    #pragma unroll
    for (int e = 0; e < 8; ++e)
      breg1[kk][e] = (short)f2bf(Wih1[(size_t)(gate*H_ + col)*H_ + kk*32 + kgrp*8 + e]);
  short8v bireg0[2];                         // Wih0 B-frags (K=64)
  #pragma unroll
  for (int kk = 0; kk < 2; ++kk)
    #pragma unroll
    for (int e = 0; e < 8; ++e)
      bireg0[kk][e] = (short)f2bf(Wih0[(size_t)(gate*H_ + col)*I_ + kk*32 + kgrp*8 + e]);

  const float bias0 = bih0[gate*H_ + col] + bhh0[gate*H_ + col];
  const float bias1 = bih1[gate*H_ + col] + bhh1[gate*H_ + col];

  float c1[4] = {0.f,0.f,0.f,0.f}, c2[4] = {0.f,0.f,0.f,0.f};

  const float* xbase = x + (size_t)(bb + n) * T_ * I_;
  float xr[16];
  #pragma unroll
  for (int e = 0; e < 8; ++e) { xr[e] = xbase[kgrp*8 + e]; xr[8+e] = xbase[32 + kgrp*8 + e]; }

  const int srow = tid >> 4;                 // staging row 0..15 (16 thr/row)
  const int l16  = tid & 15;
  unsigned int* cg = cnts + g*512;           // 32 lines/group, stride 16 u32
  const int myline = ((c & 7)*4 + w) * 16;
  const int aswz  = (n & 7) << 4;
  const int abase = n * 1024;
  const int bbase = (p*16 + n) * 1024;
  const int u64col = c*4 + p;

  for (int s = 0; s <= T_; ++s) {
    // ---- stage A1 <- h1[s-1] (parity (s+1)&1): ONE 8-deep batch, 1 LLC RT ----
    {
      const unsigned long long* s1 = hc1 + (size_t)((s+1)&1)*(B_*H_/4) + (size_t)(bb + srow)*(H_/4);
      unsigned long long tmp[8];
      #pragma unroll
      for (int jj = 0; jj < 8; ++jj)
        tmp[jj] = __hip_atomic_load(s1 + jj*16 + l16, __ATOMIC_RELAXED, __HIP_MEMORY_SCOPE_AGENT);
      #pragma unroll
      for (int jj = 0; jj < 8; ++jj) {
        int bo = (srow*1024 + (jj*16 + l16)*8) ^ ((srow & 7) << 4);
        *(unsigned long long*)((char*)A1 + bo) = tmp[jj];
      }
    }
    __syncthreads();

    // ---- L0 step s: gates = [x_t | h1[s-1]] @ [Wih0 | Whh0]^T ----
    if (s < T_) {
      f32x4 acc = {0.f,0.f,0.f,0.f};
      #pragma unroll
      for (int kk = 0; kk < 2; ++kk) {
        short8v a;
        #pragma unroll
        for (int e = 0; e < 8; ++e) a[e] = (short)f2bf(xr[kk*8 + e]);
        acc = __builtin_amdgcn_mfma_f32_16x16x32_bf16(a, bireg0[kk], acc, 0, 0, 0);
      }
      #pragma unroll
      for (int kk = 0; kk < 16; ++kk) {
        short8v a = *(const short8v*)((const char*)A1 + ((abase + kk*64 + kgrp*16) ^ aswz));
        short8v b = *(const short8v*)((const char*)W0 + ((bbase + kk*64 + kgrp*16) ^ aswz));
        acc = __builtin_amdgcn_mfma_f32_16x16x32_bf16(a, b, acc, 0, 0, 0);
      }
      float hv[4];
      cell_update(acc, bias0, gate, c1, hv);
      store_h(hv, hc1 + (size_t)(s&1)*(B_*H_/4), bb, kgrp, lane, u64col);
    }

    // ---- stage A2 <- h2[s-2] (parity s&1): latency hides under L0 tail ----
    {
      const unsigned long long* s2 = hc2 + (size_t)(s&1)*(B_*H_/4) + (size_t)(bb + srow)*(H_/4);
      unsigned long long tmp[8];
      #pragma unroll
      for (int jj = 0; jj < 8; ++jj)
        tmp[jj] = __hip_atomic_load(s2 + jj*16 + l16, __ATOMIC_RELAXED, __HIP_MEMORY_SCOPE_AGENT);
      #pragma unroll
      for (int jj = 0; jj < 8; ++jj) {
        int bo = (srow*1024 + (jj*16 + l16)*8) ^ ((srow & 7) << 4);
        *(unsigned long long*)((char*)A2 + bo) = tmp[jj];
      }
    }
    __syncthreads();

    // ---- L1 step s-1: gates = Wih1·h1[s-1] + Whh1·h2[s-2] ----
    if (s >= 1) {
      f32x4 acc = {0.f,0.f,0.f,0.f};
      #pragma unroll
      for (int kk = 0; kk < 16; ++kk) {
        short8v a = *(const short8v*)((const char*)A1 + ((abase + kk*64 + kgrp*16) ^ aswz));
        acc = __builtin_amdgcn_mfma_f32_16x16x32_bf16(a, breg1[kk], acc, 0, 0, 0);
      }
      #pragma unroll
      for (int kk = 0; kk < 16; ++kk) {
        short8v a = *(const short8v*)((const char*)A2 + ((abase + kk*64 + kgrp*16) ^ aswz));
        short8v b = *(const short8v*)((const char*)W1 + ((bbase + kk*64 + kgrp*16) ^ aswz));
        acc = __builtin_amdgcn_mfma_f32_16x16x32_bf16(a, b, acc, 0, 0, 0);
      }
      float hv[4];
      cell_update(acc, bias1, gate, c2, hv);
      if (s < T_) {
        store_h(hv, hc2 + (size_t)((s+1)&1)*(B_*H_/4), bb, kgrp, lane, u64col);
      } else if (gate == 0) {
        #pragma unroll
        for (int r = 0; r < 4; ++r)
          h2last[(size_t)(bb + kgrp*4 + r)*H_ + col] = hv[r];
      }
    }

    if (s < T_) {
      __syncthreads();                       // all waves done; stores drained/wave
      // ---- arrive: per-wave release add (orders this wave's h-stores) ----
      if (lane == 0)
        __hip_atomic_fetch_add(cg + myline, 1u, __ATOMIC_RELEASE, __HIP_MEMORY_SCOPE_AGENT);

      // ---- prefetch x for t=s+1 (overlaps other CUs' arrivals) ----
      if (s + 1 < T_) {
        const float* xp = xbase + (size_t)(s+1)*I_;
        #pragma unroll
        for (int e = 0; e < 8; ++e) { xr[e] = xp[kgrp*8 + e]; xr[8+e] = xp[32 + kgrp*8 + e]; }
      }

      // ---- wait: wave 0 sweeps 32 lines in parallel (lane i -> line i) ----
      if (w == 0) {
        const unsigned target = 128u * (unsigned)(s + 1);
        int guard = 0;
        for (;;) {
          unsigned v = 0;
          if (lane < 32)
            v = __hip_atomic_load(cg + lane*16, __ATOMIC_RELAXED, __HIP_MEMORY_SCOPE_AGENT);
          #pragma unroll
          for (int off = 16; off; off >>= 1) v += (unsigned)__shfl_xor((int)v, off, 64);
          unsigned total = (unsigned)__shfl((int)v, 0, 64);   // uniform exit
          if (total >= target) break;
          if (++guard > (1 << 15)) break;    // deadlock fuse: fail fast, never hang
          __builtin_amdgcn_s_sleep(1);
        }
      }
      __builtin_amdgcn_fence(__ATOMIC_ACQUIRE, "agent");
      __syncthreads();
    }
  }
}

__global__ void out_proj(const float* __restrict__ h2last,
                         const float* __restrict__ Wout,
                         const float* __restrict__ bout,
                         float* __restrict__ out) {
  int o = blockIdx.x;            // 0..383 = b*3+cc
  int b = o / 3, cc = o - b * 3;
  int ln = threadIdx.x;          // 64
  float s = 0.f;
  #pragma unroll
  for (int k = ln; k < H_; k += 64) s += h2last[b * H_ + k] * Wout[cc * H_ + k];
  #pragma unroll
  for (int off = 32; off; off >>= 1) s += __shfl_down(s, off, 64);
  if (ln == 0) out[o] = s + bout[cc];
}

extern "C" void kernel_launch(void* const* d_in, const int* in_sizes, int n_in,
                              void* d_out, int out_size, void* d_ws, size_t ws_size,
                              hipStream_t stream) {
  (void)in_sizes; (void)n_in; (void)out_size; (void)ws_size;
  const float* x    = (const float*)d_in[0];
  const float* Wih0 = (const float*)d_in[1];
  const float* Whh0 = (const float*)d_in[2];
  const float* bih0 = (const float*)d_in[3];
  const float* bhh0 = (const float*)d_in[4];
  const float* Wih1 = (const float*)d_in[5];
  const float* Whh1 = (const float*)d_in[6];
  const float* bih1 = (const float*)d_in[7];
  const float* bhh1 = (const float*)d_in[8];
  const float* Wout = (const float*)d_in[9];
  const float* bout = (const float*)d_in[10];

  char* ws = (char*)d_ws;
  unsigned long long* hc1 = (unsigned long long*)(ws);            // 262144 B
  unsigned long long* hc2 = (unsigned long long*)(ws + 262144);   // 262144 B
  unsigned int* cnts      = (unsigned int*)(ws + 524288);         // 16384 B (8 x 2KB)
  float* h2last           = (float*)(ws + 540672);                // 262144 B

  // zero h ping-pongs (h_init = 0) + barrier counters, every launch
  hipMemsetAsync(ws, 0, 540672, stream);

  void* args[13] = {
    (void*)&Wih0, (void*)&Whh0, (void*)&bih0, (void*)&bhh0,
    (void*)&Wih1, (void*)&Whh1, (void*)&bih1, (void*)&bhh1,
    (void*)&x, (void*)&hc1, (void*)&hc2, (void*)&h2last, (void*)&cnts
  };
  hipLaunchCooperativeKernel(reinterpret_cast<const void*>(&lstm_fused),
                             dim3(256), dim3(256), args, 0, stream);
  out_proj<<<dim3(384), dim3(64), 0, stream>>>(h2last, Wout, bout, (float*)d_out);
}